// Round 5
// baseline (563.955 us; speedup 1.0000x reference)
//
#include <hip/hip_runtime.h>
#include <hip/hip_bf16.h>

#define E_ 8
#define H_ 2048
#define I_ 5632
#define B_ 1024
#define K_ 2
#define NROWS (B_*K_)

#define BM 320
#define BN 64
#define BK 64
#define MAXT2 14          // sum_e ceil(cnt_e/320) <= floor(2048/320)+8 = 14
#define NKG (H_/BK)       // 32
#define NKD (I_/BK)       // 88
#define NYG (I_/BN)       // 88
#define NYD (H_/BN)       // 32

typedef __attribute__((ext_vector_type(8))) __bf16 bf16x8;
typedef __attribute__((ext_vector_type(4))) float f32x4;
typedef __attribute__((ext_vector_type(2))) float f32x2;

union BF4 { __bf16 b[4]; uint2 q; };
union BF8 { __bf16 b[8]; uint4 q; };

__device__ __forceinline__ void gld_lds16(const void* g, void* l) {
  __builtin_amdgcn_global_load_lds(
      (const __attribute__((address_space(1))) void*)g,
      (__attribute__((address_space(3))) void*)l, 16, 0, 0);
}

#define GLOAD2(dst, ptr) asm volatile("global_load_dwordx2 %0, %1, off" : "=v"(dst) : "v"(ptr))
#define WAITV(N) do { asm volatile("s_waitcnt vmcnt(" #N ")" ::: "memory"); __builtin_amdgcn_sched_barrier(0); } while(0)
#define WAITL()  do { asm volatile("s_waitcnt lgkmcnt(0)" ::: "memory"); __builtin_amdgcn_sched_barrier(0); } while(0)
#define BAR()    __builtin_amdgcn_s_barrier()

// ---------------- phase 0: x (f32) -> xb (bf16) ----------------
__global__ void cvtx_kernel(const float* __restrict__ x, __bf16* __restrict__ xb) {
  int i = (blockIdx.x * 256 + threadIdx.x) * 8;
  float4 a = *(const float4*)(x + i);
  float4 b = *(const float4*)(x + i + 4);
  BF8 r;
  r.b[0] = (__bf16)a.x; r.b[1] = (__bf16)a.y; r.b[2] = (__bf16)a.z; r.b[3] = (__bf16)a.w;
  r.b[4] = (__bf16)b.x; r.b[5] = (__bf16)b.y; r.b[6] = (__bf16)b.z; r.b[7] = (__bf16)b.w;
  *(uint4*)(xb + i) = r.q;
}

// ---------------- phase 1: routing + dense tile list (BM=320) ----------------
__global__ void route_kernel(const int* __restrict__ ids,
                             int* __restrict__ counts, int* __restrict__ offsets,
                             int* __restrict__ tlist, int* __restrict__ row_of,
                             int* __restrict__ tile_e, int* __restrict__ tile_m) {
  __shared__ int sc[E_], sp[E_], so[E_];
  int t = threadIdx.x;
  if (t < E_) { sc[t] = 0; sp[t] = 0; }
  __syncthreads();
  for (int idx = t; idx < NROWS; idx += 256) atomicAdd(&sc[ids[idx]], 1);
  __syncthreads();
  if (t == 0) {
    int acc = 0;
    for (int e = 0; e < E_; ++e) { so[e] = acc; acc += sc[e]; }
    int nt = 0;
    for (int e = 0; e < E_; ++e)
      for (int m0 = 0; m0 < sc[e]; m0 += BM) { tile_e[nt] = e; tile_m[nt] = m0; ++nt; }
    for (; nt < MAXT2; ++nt) { tile_e[nt] = 0; tile_m[nt] = 0x7FFFFFFF; }
  }
  __syncthreads();
  for (int idx = t; idx < NROWS; idx += 256) {
    int e = ids[idx];
    int slot = atomicAdd(&sp[e], 1);
    int row = so[e] + slot;
    tlist[row] = idx / K_;
    row_of[idx] = row;
  }
  if (t < E_) { counts[t] = sc[t]; offsets[t] = so[t]; }
}

// ---------------- phase 2: gate+up dual GEMM + SiLU (bf16 act) ----------------
// 512 thr (8 waves 4m x 2n over 320x64), raw-barrier counted-vmcnt pipeline.
// Per-wave steady-state outstanding VMEM = 13 (PF:8 + GLDA:5), never drained.
__global__ __launch_bounds__(512, 1) void gateup_kernel(
    const __bf16* __restrict__ xb, const float* __restrict__ gw,
    const float* __restrict__ uw, const int* __restrict__ counts,
    const int* __restrict__ offsets, const int* __restrict__ tlist,
    const int* __restrict__ tile_e, const int* __restrict__ tile_m,
    __bf16* __restrict__ act)
{
  extern __shared__ char smem[];
  char* As0 = smem;                 // 40960 each (320 rows x 128B, swizzled)
  char* As1 = smem + 40960;
  char* Bg0 = smem + 81920;         // 8192 each (64 cols x 128B col-major, swizzled)
  char* Bg1 = smem + 90112;
  char* Bu0 = smem + 98304;
  char* Bu1 = smem + 106496;

  const int id = blockIdx.x;                  // [0, 1232)
  const int w  = (id & 7) * 154 + (id >> 3);  // XCD chunking
  const int tt = w / NYG;                     // [0,14)
  const int ny = w % NYG;
  const int e  = tile_e[tt];
  const int m0 = tile_m[tt];
  const int cnt = counts[e];
  if (m0 >= cnt) return;
  const int off = offsets[e];
  const int n0 = ny * BN;

  const int tid  = threadIdx.x;
  const int lane = tid & 63;
  const int wave = tid >> 6;         // 0..7
  const int wm = wave >> 1;          // 0..3 -> rows wm*80
  const int wn = wave & 1;           // cols wn*32

  // ---- A staging setup: 5 granules/thread, LDS linear, source slot-swizzled
  const __bf16* asrc0; const __bf16* asrc1; const __bf16* asrc2;
  const __bf16* asrc3; const __bf16* asrc4;
  int ad0, ad1, ad2, ad3, ad4;
  {
    const __bf16* s[5]; int d[5];
#pragma unroll
    for (int i = 0; i < 5; ++i) {
      int f = i*512 + tid;
      int r = f >> 3, cs = f & 7;
      int rr = m0 + r; if (rr >= cnt) rr = cnt - 1;
      int tok = tlist[off + rr];
      s[i] = xb + (size_t)tok * H_ + ((cs ^ (r & 7)) << 3);
      d[i] = f * 16;
    }
    asrc0=s[0]; asrc1=s[1]; asrc2=s[2]; asrc3=s[3]; asrc4=s[4];
    ad0=d[0]; ad1=d[1]; ad2=d[2]; ad3=d[3]; ad4=d[4];
  }

  // ---- B staging setup: thread owns cols {2c2,2c2+1}, k rows kb..kb+3
  const int c2 = tid & 31;
  const int kb = (tid >> 5) * 4;     // 0..60
  const float* pg0 = gw + ((size_t)e*H_ + kb + 0)*I_ + n0 + 2*c2;
  const float* pg1 = gw + ((size_t)e*H_ + kb + 1)*I_ + n0 + 2*c2;
  const float* pg2 = gw + ((size_t)e*H_ + kb + 2)*I_ + n0 + 2*c2;
  const float* pg3 = gw + ((size_t)e*H_ + kb + 3)*I_ + n0 + 2*c2;
  const float* pu0 = uw + ((size_t)e*H_ + kb + 0)*I_ + n0 + 2*c2;
  const float* pu1 = uw + ((size_t)e*H_ + kb + 1)*I_ + n0 + 2*c2;
  const float* pu2 = uw + ((size_t)e*H_ + kb + 2)*I_ + n0 + 2*c2;
  const float* pu3 = uw + ((size_t)e*H_ + kb + 3)*I_ + n0 + 2*c2;
  const int slot = kb >> 3;
  const int half = (kb & 4) << 1;    // 0 or 8
  const int cA = 2*c2, cB = 2*c2 + 1;
  const int bwA = cA*128 + ((slot ^ (cA & 7)) << 4) + half;
  const int bwB = cB*128 + ((slot ^ (cB & 7)) << 4) + half;

  f32x2 vgA_0,vgA_1,vgA_2,vgA_3, vuA_0,vuA_1,vuA_2,vuA_3;
  f32x2 vgB_0,vgB_1,vgB_2,vgB_3, vuB_0,vuB_1,vuB_2,vuB_3;

  f32x4 accg[5][2], accu[5][2];
#pragma unroll
  for (int i = 0; i < 5; ++i)
#pragma unroll
    for (int j = 0; j < 2; ++j) {
      accg[i][j] = (f32x4){0.f,0.f,0.f,0.f};
      accu[i][j] = (f32x4){0.f,0.f,0.f,0.f};
    }

  auto COMPUTE = [&](const char* Ab, const char* Bgb, const char* Bub) {
#pragma unroll
    for (int kk = 0; kk < 2; ++kk) {
      const int ks = kk*4 + (lane >> 4);
      const int r0 = wm*80 + (lane & 15);
      const int swa = (ks ^ (r0 & 7)) << 4;
      bf16x8 a0 = *(const bf16x8*)(Ab + (r0 +  0)*128 + swa);
      bf16x8 a1 = *(const bf16x8*)(Ab + (r0 + 16)*128 + swa);
      bf16x8 a2 = *(const bf16x8*)(Ab + (r0 + 32)*128 + swa);
      bf16x8 a3 = *(const bf16x8*)(Ab + (r0 + 48)*128 + swa);
      bf16x8 a4 = *(const bf16x8*)(Ab + (r0 + 64)*128 + swa);
      const int c0 = wn*32 + (lane & 15);
      const int swb = (ks ^ (c0 & 7)) << 4;
      bf16x8 g0 = *(const bf16x8*)(Bgb + c0*128 + swb);
      bf16x8 g1 = *(const bf16x8*)(Bgb + (c0+16)*128 + swb);
      bf16x8 u0 = *(const bf16x8*)(Bub + c0*128 + swb);
      bf16x8 u1 = *(const bf16x8*)(Bub + (c0+16)*128 + swb);
      accg[0][0] = __builtin_amdgcn_mfma_f32_16x16x32_bf16(a0, g0, accg[0][0], 0,0,0);
      accg[1][0] = __builtin_amdgcn_mfma_f32_16x16x32_bf16(a1, g0, accg[1][0], 0,0,0);
      accg[2][0] = __builtin_amdgcn_mfma_f32_16x16x32_bf16(a2, g0, accg[2][0], 0,0,0);
      accg[3][0] = __builtin_amdgcn_mfma_f32_16x16x32_bf16(a3, g0, accg[3][0], 0,0,0);
      accg[4][0] = __builtin_amdgcn_mfma_f32_16x16x32_bf16(a4, g0, accg[4][0], 0,0,0);
      accg[0][1] = __builtin_amdgcn_mfma_f32_16x16x32_bf16(a0, g1, accg[0][1], 0,0,0);
      accg[1][1] = __builtin_amdgcn_mfma_f32_16x16x32_bf16(a1, g1, accg[1][1], 0,0,0);
      accg[2][1] = __builtin_amdgcn_mfma_f32_16x16x32_bf16(a2, g1, accg[2][1], 0,0,0);
      accg[3][1] = __builtin_amdgcn_mfma_f32_16x16x32_bf16(a3, g1, accg[3][1], 0,0,0);
      accg[4][1] = __builtin_amdgcn_mfma_f32_16x16x32_bf16(a4, g1, accg[4][1], 0,0,0);
      accu[0][0] = __builtin_amdgcn_mfma_f32_16x16x32_bf16(a0, u0, accu[0][0], 0,0,0);
      accu[1][0] = __builtin_amdgcn_mfma_f32_16x16x32_bf16(a1, u0, accu[1][0], 0,0,0);
      accu[2][0] = __builtin_amdgcn_mfma_f32_16x16x32_bf16(a2, u0, accu[2][0], 0,0,0);
      accu[3][0] = __builtin_amdgcn_mfma_f32_16x16x32_bf16(a3, u0, accu[3][0], 0,0,0);
      accu[4][0] = __builtin_amdgcn_mfma_f32_16x16x32_bf16(a4, u0, accu[4][0], 0,0,0);
      accu[0][1] = __builtin_amdgcn_mfma_f32_16x16x32_bf16(a0, u1, accu[0][1], 0,0,0);
      accu[1][1] = __builtin_amdgcn_mfma_f32_16x16x32_bf16(a1, u1, accu[1][1], 0,0,0);
      accu[2][1] = __builtin_amdgcn_mfma_f32_16x16x32_bf16(a2, u1, accu[2][1], 0,0,0);
      accu[3][1] = __builtin_amdgcn_mfma_f32_16x16x32_bf16(a3, u1, accu[3][1], 0,0,0);
      accu[4][1] = __builtin_amdgcn_mfma_f32_16x16x32_bf16(a4, u1, accu[4][1], 0,0,0);
    }
  };

#define GU_PF(S, KPF) do { size_t o_ = (size_t)(KPF)*(size_t)BK*(size_t)I_; \
    GLOAD2(vg##S##_0, pg0+o_); GLOAD2(vu##S##_0, pu0+o_); \
    GLOAD2(vg##S##_1, pg1+o_); GLOAD2(vu##S##_1, pu1+o_); \
    GLOAD2(vg##S##_2, pg2+o_); GLOAD2(vu##S##_2, pu2+o_); \
    GLOAD2(vg##S##_3, pg3+o_); GLOAD2(vu##S##_3, pu3+o_); } while(0)

#define GU_CVW(S, BG, BU) do { BF4 x_, y_, z_, t_; \
    x_.b[0]=(__bf16)vg##S##_0.x; x_.b[1]=(__bf16)vg##S##_1.x; x_.b[2]=(__bf16)vg##S##_2.x; x_.b[3]=(__bf16)vg##S##_3.x; \
    y_.b[0]=(__bf16)vg##S##_0.y; y_.b[1]=(__bf16)vg##S##_1.y; y_.b[2]=(__bf16)vg##S##_2.y; y_.b[3]=(__bf16)vg##S##_3.y; \
    z_.b[0]=(__bf16)vu##S##_0.x; z_.b[1]=(__bf16)vu##S##_1.x; z_.b[2]=(__bf16)vu##S##_2.x; z_.b[3]=(__bf16)vu##S##_3.x; \
    t_.b[0]=(__bf16)vu##S##_0.y; t_.b[1]=(__bf16)vu##S##_1.y; t_.b[2]=(__bf16)vu##S##_2.y; t_.b[3]=(__bf16)vu##S##_3.y; \
    *(uint2*)((BG)+bwA) = x_.q; *(uint2*)((BG)+bwB) = y_.q; \
    *(uint2*)((BU)+bwA) = z_.q; *(uint2*)((BU)+bwB) = t_.q; } while(0)

#define GU_GLDA(DST, KPF) do { size_t k_ = (size_t)(KPF)*(size_t)BK; \
    gld_lds16(asrc0 + k_, (DST)+ad0); gld_lds16(asrc1 + k_, (DST)+ad1); \
    gld_lds16(asrc2 + k_, (DST)+ad2); gld_lds16(asrc3 + k_, (DST)+ad3); \
    gld_lds16(asrc4 + k_, (DST)+ad4); } while(0)

  // ---- prologue: A(0),B(0) staged; B(1) in flight (setB); A(1) in flight
  GU_PF(A, 0);
  GU_GLDA(As0, 0);
  WAITV(5);            // PF(0) done; GLDA(0):5 outstanding
  GU_CVW(A, Bg0, Bu0);
  GU_PF(B, 1);
  GU_GLDA(As1, 1);
  WAITV(13);           // GLDA(0) done; out = PF(1):8 + GLDA(1):5 = 13
  WAITL();
  BAR();

#pragma unroll 1
  for (int kt = 0; kt < NKG; kt += 2) {
    { // even: compute buf0, consume setB, fill setA
      int kpf = kt + 2; if (kpf > NKG-1) kpf = NKG-1;
      GU_PF(A, kpf);
      COMPUTE(As0, Bg0, Bu0);
      WAITV(13);                 // PF(kt+1)=setB done; keep GLDA(kt+1)+PF(kt+2)
      GU_CVW(B, Bg1, Bu1);
      WAITL();
      BAR();
      GU_GLDA(As0, kpf);
      WAITV(13);                 // GLDA(kt+1) done; keep PF(kt+2)+GLDA(kt+2)
      BAR();
    }
    { // odd: compute buf1, consume setA, fill setB
      int kpf = kt + 3; if (kpf > NKG-1) kpf = NKG-1;
      GU_PF(B, kpf);
      COMPUTE(As1, Bg1, Bu1);
      WAITV(13);
      GU_CVW(A, Bg0, Bu0);
      WAITL();
      BAR();
      GU_GLDA(As1, kpf);
      WAITV(13);
      BAR();
    }
  }
  WAITV(0);
  WAITL();

  // ---- epilogue: SiLU(g)*u -> bf16 act
  const int rsub = (lane >> 4) * 4;
  const int csub = lane & 15;
#pragma unroll
  for (int mi = 0; mi < 5; ++mi)
#pragma unroll
    for (int j = 0; j < 4; ++j) {
      int rl = wm*80 + mi*16 + rsub + j;
      if (m0 + rl < cnt) {
        size_t orow = (size_t)(off + m0 + rl) * I_ + n0 + wn*32 + csub;
#pragma unroll
        for (int cg = 0; cg < 2; ++cg) {
          float g = accg[mi][cg][j];
          float u = accu[mi][cg][j];
          float sg = g / (1.0f + __expf(-g));
          act[orow + cg*16] = (__bf16)(sg * u);
        }
      }
    }
#undef GU_PF
#undef GU_CVW
#undef GU_GLDA
}

// ---------------- phase 3: down GEMM -> rowbuf (f32) ----------------
__global__ __launch_bounds__(512, 1) void down_kernel(
    const __bf16* __restrict__ act, const float* __restrict__ dw,
    const int* __restrict__ counts, const int* __restrict__ offsets,
    const int* __restrict__ tile_e, const int* __restrict__ tile_m,
    float* __restrict__ rowbuf)
{
  extern __shared__ char smem[];
  char* As0 = smem;
  char* As1 = smem + 40960;
  char* Bs0 = smem + 81920;
  char* Bs1 = smem + 90112;

  const int id = blockIdx.x;                  // [0, 448)
  const int w  = (id & 7) * 56 + (id >> 3);
  const int tt = w / NYD;                     // [0,14)
  const int ny = w % NYD;
  const int e  = tile_e[tt];
  const int m0 = tile_m[tt];
  const int cnt = counts[e];
  if (m0 >= cnt) return;
  const int off = offsets[e];
  const int n0 = ny * BN;

  const int tid  = threadIdx.x;
  const int lane = tid & 63;
  const int wave = tid >> 6;
  const int wm = wave >> 1;
  const int wn = wave & 1;

  const __bf16* asrc0; const __bf16* asrc1; const __bf16* asrc2;
  const __bf16* asrc3; const __bf16* asrc4;
  int ad0, ad1, ad2, ad3, ad4;
  {
    const __bf16* s[5]; int d[5];
#pragma unroll
    for (int i = 0; i < 5; ++i) {
      int f = i*512 + tid;
      int r = f >> 3, cs = f & 7;
      int rr = m0 + r; if (rr >= cnt) rr = cnt - 1;
      s[i] = act + (size_t)(off + rr) * I_ + ((cs ^ (r & 7)) << 3);
      d[i] = f * 16;
    }
    asrc0=s[0]; asrc1=s[1]; asrc2=s[2]; asrc3=s[3]; asrc4=s[4];
    ad0=d[0]; ad1=d[1]; ad2=d[2]; ad3=d[3]; ad4=d[4];
  }

  const int c2 = tid & 31;
  const int kb = (tid >> 5) * 4;
  const float* pd0 = dw + ((size_t)e*I_ + kb + 0)*H_ + n0 + 2*c2;
  const float* pd1 = dw + ((size_t)e*I_ + kb + 1)*H_ + n0 + 2*c2;
  const float* pd2 = dw + ((size_t)e*I_ + kb + 2)*H_ + n0 + 2*c2;
  const float* pd3 = dw + ((size_t)e*I_ + kb + 3)*H_ + n0 + 2*c2;
  const int slot = kb >> 3;
  const int half = (kb & 4) << 1;
  const int cA = 2*c2, cB = 2*c2 + 1;
  const int bwA = cA*128 + ((slot ^ (cA & 7)) << 4) + half;
  const int bwB = cB*128 + ((slot ^ (cB & 7)) << 4) + half;

  f32x2 vdA_0,vdA_1,vdA_2,vdA_3;
  f32x2 vdB_0,vdB_1,vdB_2,vdB_3;

  f32x4 acc[5][2];
#pragma unroll
  for (int i = 0; i < 5; ++i)
#pragma unroll
    for (int j = 0; j < 2; ++j) acc[i][j] = (f32x4){0.f,0.f,0.f,0.f};

  auto COMPUTE = [&](const char* Ab, const char* Bb) {
#pragma unroll
    for (int kk = 0; kk < 2; ++kk) {
      const int ks = kk*4 + (lane >> 4);
      const int r0 = wm*80 + (lane & 15);
      const int swa = (ks ^ (r0 & 7)) << 4;
      bf16x8 a0 = *(const bf16x8*)(Ab + (r0 +  0)*128 + swa);
      bf16x8 a1 = *(const bf16x8*)(Ab + (r0 + 16)*128 + swa);
      bf16x8 a2 = *(const bf16x8*)(Ab + (r0 + 32)*128 + swa);
      bf16x8 a3 = *(const bf16x8*)(Ab + (r0 + 48)*128 + swa);
      bf16x8 a4 = *(const bf16x8*)(Ab + (r0 + 64)*128 + swa);
      const int c0 = wn*32 + (lane & 15);
      const int swb = (ks ^ (c0 & 7)) << 4;
      bf16x8 b0 = *(const bf16x8*)(Bb + c0*128 + swb);
      bf16x8 b1 = *(const bf16x8*)(Bb + (c0+16)*128 + swb);
      acc[0][0] = __builtin_amdgcn_mfma_f32_16x16x32_bf16(a0, b0, acc[0][0], 0,0,0);
      acc[1][0] = __builtin_amdgcn_mfma_f32_16x16x32_bf16(a1, b0, acc[1][0], 0,0,0);
      acc[2][0] = __builtin_amdgcn_mfma_f32_16x16x32_bf16(a2, b0, acc[2][0], 0,0,0);
      acc[3][0] = __builtin_amdgcn_mfma_f32_16x16x32_bf16(a3, b0, acc[3][0], 0,0,0);
      acc[4][0] = __builtin_amdgcn_mfma_f32_16x16x32_bf16(a4, b0, acc[4][0], 0,0,0);
      acc[0][1] = __builtin_amdgcn_mfma_f32_16x16x32_bf16(a0, b1, acc[0][1], 0,0,0);
      acc[1][1] = __builtin_amdgcn_mfma_f32_16x16x32_bf16(a1, b1, acc[1][1], 0,0,0);
      acc[2][1] = __builtin_amdgcn_mfma_f32_16x16x32_bf16(a2, b1, acc[2][1], 0,0,0);
      acc[3][1] = __builtin_amdgcn_mfma_f32_16x16x32_bf16(a3, b1, acc[3][1], 0,0,0);
      acc[4][1] = __builtin_amdgcn_mfma_f32_16x16x32_bf16(a4, b1, acc[4][1], 0,0,0);
    }
  };

#define DN_PF(S, KPF) do { size_t o_ = (size_t)(KPF)*(size_t)BK*(size_t)H_; \
    GLOAD2(vd##S##_0, pd0+o_); GLOAD2(vd##S##_1, pd1+o_); \
    GLOAD2(vd##S##_2, pd2+o_); GLOAD2(vd##S##_3, pd3+o_); } while(0)

#define DN_CVW(S, BB) do { BF4 x_, y_; \
    x_.b[0]=(__bf16)vd##S##_0.x; x_.b[1]=(__bf16)vd##S##_1.x; x_.b[2]=(__bf16)vd##S##_2.x; x_.b[3]=(__bf16)vd##S##_3.x; \
    y_.b[0]=(__bf16)vd##S##_0.y; y_.b[1]=(__bf16)vd##S##_1.y; y_.b[2]=(__bf16)vd##S##_2.y; y_.b[3]=(__bf16)vd##S##_3.y; \
    *(uint2*)((BB)+bwA) = x_.q; *(uint2*)((BB)+bwB) = y_.q; } while(0)

#define DN_GLDA(DST, KPF) do { size_t k_ = (size_t)(KPF)*(size_t)BK; \
    gld_lds16(asrc0 + k_, (DST)+ad0); gld_lds16(asrc1 + k_, (DST)+ad1); \
    gld_lds16(asrc2 + k_, (DST)+ad2); gld_lds16(asrc3 + k_, (DST)+ad3); \
    gld_lds16(asrc4 + k_, (DST)+ad4); } while(0)

  DN_PF(A, 0);
  DN_GLDA(As0, 0);
  WAITV(5);             // PF(0):4 done; GLDA(0):5 out
  DN_CVW(A, Bs0);
  DN_PF(B, 1);
  DN_GLDA(As1, 1);
  WAITV(9);             // GLDA(0) done; out = PF(1):4 + GLDA(1):5 = 9
  WAITL();
  BAR();

#pragma unroll 1
  for (int kt = 0; kt < NKD; kt += 2) {
    {
      int kpf = kt + 2; if (kpf > NKD-1) kpf = NKD-1;
      DN_PF(A, kpf);
      COMPUTE(As0, Bs0);
      WAITV(9);
      DN_CVW(B, Bs1);
      WAITL();
      BAR();
      DN_GLDA(As0, kpf);
      WAITV(9);
      BAR();
    }
    {
      int kpf = kt + 3; if (kpf > NKD-1) kpf = NKD-1;
      DN_PF(B, kpf);
      COMPUTE(As1, Bs1);
      WAITV(9);
      DN_CVW(A, Bs0);
      WAITL();
      BAR();
      DN_GLDA(As1, kpf);
      WAITV(9);
      BAR();
    }
  }
  WAITV(0);
  WAITL();

  const int rsub = (lane >> 4) * 4;
  const int csub = lane & 15;
#pragma unroll
  for (int mi = 0; mi < 5; ++mi)
#pragma unroll
    for (int j = 0; j < 4; ++j) {
      int rl = wm*80 + mi*16 + rsub + j;
      if (m0 + rl < cnt) {
        size_t orow = (size_t)(off + m0 + rl) * H_ + n0 + wn*32 + csub;
#pragma unroll
        for (int cg = 0; cg < 2; ++cg)
          rowbuf[orow + cg*16] = acc[mi][cg][j];
      }
    }
#undef DN_PF
#undef DN_CVW
#undef DN_GLDA
}

// ---------------- phase 4: weighted combine ----------------
__global__ void combine_kernel(const float* __restrict__ ew, const int* __restrict__ row_of,
                               const float* __restrict__ rowbuf, float* __restrict__ out) {
  int idx = blockIdx.x * 256 + threadIdx.x;   // over B_*H_/4
  int t  = idx >> 9;                          // H_/4 = 512
  int h4 = idx & 511;
  float w0 = ew[t*2+0], w1 = ew[t*2+1];
  int r0 = row_of[t*2+0], r1 = row_of[t*2+1];
  float4 a = *(const float4*)(rowbuf + (size_t)r0*H_ + h4*4);
  float4 b = *(const float4*)(rowbuf + (size_t)r1*H_ + h4*4);
  float4 o;
  o.x = w0*a.x + w1*b.x; o.y = w0*a.y + w1*b.y;
  o.z = w0*a.z + w1*b.z; o.w = w0*a.w + w1*b.w;
  *(float4*)(out + (size_t)idx*4) = o;
}

extern "C" void kernel_launch(void* const* d_in, const int* in_sizes, int n_in,
                              void* d_out, int out_size, void* d_ws, size_t ws_size,
                              hipStream_t stream) {
  const float* x   = (const float*)d_in[0];
  const int*   ids = (const int*)d_in[1];
  const float* ew  = (const float*)d_in[2];
  const float* gw  = (const float*)d_in[3];
  const float* uw  = (const float*)d_in[4];
  const float* dwn = (const float*)d_in[5];
  float* out = (float*)d_out;

  char* ws = (char*)d_ws;
  int* counts  = (int*)ws;          // 8
  int* offsets = counts + 8;        // 8
  int* tlist   = offsets + 8;       // NROWS
  int* row_of  = tlist + NROWS;     // NROWS
  int* tile_e  = row_of + NROWS;    // MAXT2
  int* tile_m  = tile_e + MAXT2;    // MAXT2
  __bf16* xb   = (__bf16*)(ws + 32768);
  __bf16* act  = (__bf16*)(ws + 32768 + (size_t)B_*H_*2);
  float* rowbuf = (float*)(ws + 32768 + (size_t)B_*H_*2 + (size_t)NROWS*I_*2);

  hipFuncSetAttribute(reinterpret_cast<const void*>(&gateup_kernel),
                      hipFuncAttributeMaxDynamicSharedMemorySize, 114688);
  hipFuncSetAttribute(reinterpret_cast<const void*>(&down_kernel),
                      hipFuncAttributeMaxDynamicSharedMemorySize, 98304);

  cvtx_kernel<<<B_*H_/(256*8), 256, 0, stream>>>(x, xb);
  route_kernel<<<1, 256, 0, stream>>>(ids, counts, offsets, tlist, row_of, tile_e, tile_m);

  gateup_kernel<<<MAXT2*NYG, 512, 114688, stream>>>(xb, gw, uw, counts, offsets, tlist,
                                                    tile_e, tile_m, act);

  down_kernel<<<MAXT2*NYD, 512, 98304, stream>>>(act, dwn, counts, offsets,
                                                 tile_e, tile_m, rowbuf);

  combine_kernel<<<(B_*H_/4)/256, 256, 0, stream>>>(ew, row_of, rowbuf, out);
}

// Round 6
// 449.494 us; speedup vs baseline: 1.2546x; 1.2546x over previous
//
#include <hip/hip_runtime.h>
#include <hip/hip_bf16.h>

#define E_ 8
#define H_ 2048
#define I_ 5632
#define B_ 1024
#define K_ 2
#define NROWS (B_*K_)

#define BM 128
#define BN 64
#define BK 64
#define MAXT 24           // sum_e ceil(cnt_e/128) <= 16 + 8
#define NKG (H_/BK)       // 32
#define NKD (I_/BK)       // 88
#define NYG (I_/BN)       // 88
#define NYD (H_/BN)       // 32

typedef __attribute__((ext_vector_type(8))) __bf16 bf16x8;
typedef __attribute__((ext_vector_type(4))) float f32x4;

union BF4 { __bf16 b[4]; uint2 q; };
union BF8 { __bf16 b[8]; uint4 q; };

__device__ __forceinline__ void gld_lds16(const void* g, void* l) {
  __builtin_amdgcn_global_load_lds(
      (const __attribute__((address_space(1))) void*)g,
      (__attribute__((address_space(3))) void*)l, 16, 0, 0);
}

#define GLOAD4(dst, ptr) asm volatile("global_load_dwordx4 %0, %1, off" : "=v"(dst) : "v"(ptr))
#define WAITV(N) do { asm volatile("s_waitcnt vmcnt(" #N ")" ::: "memory"); __builtin_amdgcn_sched_barrier(0); } while(0)
#define WAITL()  do { asm volatile("s_waitcnt lgkmcnt(0)" ::: "memory"); __builtin_amdgcn_sched_barrier(0); } while(0)
#define BAR()    __builtin_amdgcn_s_barrier()

// ---------------- phase 0: x (f32) -> xb (bf16) ----------------
__global__ void cvtx_kernel(const float* __restrict__ x, __bf16* __restrict__ xb) {
  int i = (blockIdx.x * 256 + threadIdx.x) * 8;
  float4 a = *(const float4*)(x + i);
  float4 b = *(const float4*)(x + i + 4);
  BF8 r;
  r.b[0] = (__bf16)a.x; r.b[1] = (__bf16)a.y; r.b[2] = (__bf16)a.z; r.b[3] = (__bf16)a.w;
  r.b[4] = (__bf16)b.x; r.b[5] = (__bf16)b.y; r.b[6] = (__bf16)b.z; r.b[7] = (__bf16)b.w;
  *(uint4*)(xb + i) = r.q;
}

// ---------------- phase 1: routing + dense tile list ----------------
__global__ void route_kernel(const int* __restrict__ ids,
                             int* __restrict__ counts, int* __restrict__ offsets,
                             int* __restrict__ tlist, int* __restrict__ row_of,
                             int* __restrict__ tile_e, int* __restrict__ tile_m) {
  __shared__ int sc[E_], sp[E_], so[E_];
  int t = threadIdx.x;
  if (t < E_) { sc[t] = 0; sp[t] = 0; }
  __syncthreads();
  for (int idx = t; idx < NROWS; idx += 256) atomicAdd(&sc[ids[idx]], 1);
  __syncthreads();
  if (t == 0) {
    int acc = 0;
    for (int e = 0; e < E_; ++e) { so[e] = acc; acc += sc[e]; }
    int nt = 0;
    for (int e = 0; e < E_; ++e)
      for (int m0 = 0; m0 < sc[e]; m0 += BM) { tile_e[nt] = e; tile_m[nt] = m0; ++nt; }
    for (; nt < MAXT; ++nt) { tile_e[nt] = 0; tile_m[nt] = 0x7FFFFFFF; }
  }
  __syncthreads();
  for (int idx = t; idx < NROWS; idx += 256) {
    int e = ids[idx];
    int slot = atomicAdd(&sp[e], 1);
    int row = so[e] + slot;
    tlist[row] = idx / K_;
    row_of[idx] = row;
  }
  if (t < E_) { counts[t] = sc[t]; offsets[t] = so[t]; }
}

// ---------------- phase 2: gate+up dual GEMM + SiLU (bf16 act) ----------------
// 256 thr (4 waves 2m x 2n over 128x64), 64 KB LDS -> 2 blocks/CU.
// Counted-vmcnt: steady outstanding 12 (PF:8 + GLDA:4), one s_barrier/k-step.
__global__ __launch_bounds__(256, 2) void gateup_kernel(
    const __bf16* __restrict__ xb, const float* __restrict__ gw,
    const float* __restrict__ uw, const int* __restrict__ counts,
    const int* __restrict__ offsets, const int* __restrict__ tlist,
    const int* __restrict__ tile_e, const int* __restrict__ tile_m,
    __bf16* __restrict__ act)
{
  extern __shared__ char smem[];
  char* As0 = smem;                 // 16384 each (128 rows x 128B, swizzled)
  char* As1 = smem + 16384;
  char* Bg0 = smem + 32768;         // 8192 each (64 cols x 128B, swizzled)
  char* Bg1 = smem + 40960;
  char* Bu0 = smem + 49152;
  char* Bu1 = smem + 57344;

  const int id = blockIdx.x;                  // [0, 2112)
  const int w  = (id & 7) * 264 + (id >> 3);  // XCD chunking (2112 = 8*264)
  const int tt = w % MAXT;
  const int ny = w / MAXT;                    // [0, 88)
  const int e  = tile_e[tt];
  const int m0 = tile_m[tt];
  const int cnt = counts[e];
  if (m0 >= cnt) return;
  const int off = offsets[e];
  const int n0 = ny * BN;

  const int tid  = threadIdx.x;
  const int lane = tid & 63;
  const int wave = tid >> 6;         // 0..3
  const int wr = (wave >> 1) * 64;   // 0,64
  const int wc = (wave & 1) * 32;    // 0,32

  // ---- A staging: 4 granules/thread, LDS linear, source slot-swizzled
  const __bf16* asrc0; const __bf16* asrc1; const __bf16* asrc2; const __bf16* asrc3;
  int ad0, ad1, ad2, ad3;
  {
    const __bf16* s[4]; int d[4];
#pragma unroll
    for (int i = 0; i < 4; ++i) {
      int f = i*256 + tid;
      int r = f >> 3, cs = f & 7;
      int rr = m0 + r; if (rr >= cnt) rr = cnt - 1;
      int tok = tlist[off + rr];
      s[i] = xb + (size_t)tok * H_ + ((cs ^ (r & 7)) << 3);
      d[i] = f * 16;
    }
    asrc0=s[0]; asrc1=s[1]; asrc2=s[2]; asrc3=s[3];
    ad0=d[0]; ad1=d[1]; ad2=d[2]; ad3=d[3];
  }

  // ---- B staging: thread owns cols 4cq..4cq+3, k-rows kb..kb+3 (dwordx4)
  const int cq = tid & 15;           // col-chunk of 4 floats
  const int kb = (tid >> 4) * 4;     // 0..60
  const float* pg0 = gw + ((size_t)e*H_ + kb + 0)*I_ + n0 + 4*cq;
  const float* pg1 = gw + ((size_t)e*H_ + kb + 1)*I_ + n0 + 4*cq;
  const float* pg2 = gw + ((size_t)e*H_ + kb + 2)*I_ + n0 + 4*cq;
  const float* pg3 = gw + ((size_t)e*H_ + kb + 3)*I_ + n0 + 4*cq;
  const float* pu0 = uw + ((size_t)e*H_ + kb + 0)*I_ + n0 + 4*cq;
  const float* pu1 = uw + ((size_t)e*H_ + kb + 1)*I_ + n0 + 4*cq;
  const float* pu2 = uw + ((size_t)e*H_ + kb + 2)*I_ + n0 + 4*cq;
  const float* pu3 = uw + ((size_t)e*H_ + kb + 3)*I_ + n0 + 4*cq;
  const int slot = kb >> 3;
  const int half = (kb & 4) << 1;    // 0 or 8
  int bw0, bw1, bw2, bw3;
  {
    int b[4];
#pragma unroll
    for (int i = 0; i < 4; ++i) {
      int c = 4*cq + i;
      b[i] = c*128 + ((slot ^ (c & 7)) << 4) + half;
    }
    bw0=b[0]; bw1=b[1]; bw2=b[2]; bw3=b[3];
  }

  f32x4 vgA_0,vgA_1,vgA_2,vgA_3, vuA_0,vuA_1,vuA_2,vuA_3;
  f32x4 vgB_0,vgB_1,vgB_2,vgB_3, vuB_0,vuB_1,vuB_2,vuB_3;

  f32x4 accg[4][2], accu[4][2];
#pragma unroll
  for (int i = 0; i < 4; ++i)
#pragma unroll
    for (int j = 0; j < 2; ++j) {
      accg[i][j] = (f32x4){0.f,0.f,0.f,0.f};
      accu[i][j] = (f32x4){0.f,0.f,0.f,0.f};
    }

  auto COMPUTE = [&](const char* Ab, const char* Bgb, const char* Bub) {
#pragma unroll
    for (int kk = 0; kk < 2; ++kk) {
      const int ks = kk*4 + (lane >> 4);
      const int r0 = wr + (lane & 15);
      const int swa = (ks ^ (r0 & 7)) << 4;
      bf16x8 a0 = *(const bf16x8*)(Ab + (r0 +  0)*128 + swa);
      bf16x8 a1 = *(const bf16x8*)(Ab + (r0 + 16)*128 + swa);
      bf16x8 a2 = *(const bf16x8*)(Ab + (r0 + 32)*128 + swa);
      bf16x8 a3 = *(const bf16x8*)(Ab + (r0 + 48)*128 + swa);
      const int c0 = wc + (lane & 15);
      const int swb0 = (ks ^ (c0 & 7)) << 4;
      const int swb1 = (ks ^ ((c0+16) & 7)) << 4;
      bf16x8 g0 = *(const bf16x8*)(Bgb + c0*128 + swb0);
      bf16x8 g1 = *(const bf16x8*)(Bgb + (c0+16)*128 + swb1);
      bf16x8 u0 = *(const bf16x8*)(Bub + c0*128 + swb0);
      bf16x8 u1 = *(const bf16x8*)(Bub + (c0+16)*128 + swb1);
      accg[0][0] = __builtin_amdgcn_mfma_f32_16x16x32_bf16(a0, g0, accg[0][0], 0,0,0);
      accg[1][0] = __builtin_amdgcn_mfma_f32_16x16x32_bf16(a1, g0, accg[1][0], 0,0,0);
      accg[2][0] = __builtin_amdgcn_mfma_f32_16x16x32_bf16(a2, g0, accg[2][0], 0,0,0);
      accg[3][0] = __builtin_amdgcn_mfma_f32_16x16x32_bf16(a3, g0, accg[3][0], 0,0,0);
      accg[0][1] = __builtin_amdgcn_mfma_f32_16x16x32_bf16(a0, g1, accg[0][1], 0,0,0);
      accg[1][1] = __builtin_amdgcn_mfma_f32_16x16x32_bf16(a1, g1, accg[1][1], 0,0,0);
      accg[2][1] = __builtin_amdgcn_mfma_f32_16x16x32_bf16(a2, g1, accg[2][1], 0,0,0);
      accg[3][1] = __builtin_amdgcn_mfma_f32_16x16x32_bf16(a3, g1, accg[3][1], 0,0,0);
      accu[0][0] = __builtin_amdgcn_mfma_f32_16x16x32_bf16(a0, u0, accu[0][0], 0,0,0);
      accu[1][0] = __builtin_amdgcn_mfma_f32_16x16x32_bf16(a1, u0, accu[1][0], 0,0,0);
      accu[2][0] = __builtin_amdgcn_mfma_f32_16x16x32_bf16(a2, u0, accu[2][0], 0,0,0);
      accu[3][0] = __builtin_amdgcn_mfma_f32_16x16x32_bf16(a3, u0, accu[3][0], 0,0,0);
      accu[0][1] = __builtin_amdgcn_mfma_f32_16x16x32_bf16(a0, u1, accu[0][1], 0,0,0);
      accu[1][1] = __builtin_amdgcn_mfma_f32_16x16x32_bf16(a1, u1, accu[1][1], 0,0,0);
      accu[2][1] = __builtin_amdgcn_mfma_f32_16x16x32_bf16(a2, u1, accu[2][1], 0,0,0);
      accu[3][1] = __builtin_amdgcn_mfma_f32_16x16x32_bf16(a3, u1, accu[3][1], 0,0,0);
    }
  };

#define GU_PF(S, KPF) do { size_t o_ = (size_t)(KPF)*(size_t)BK*(size_t)I_; \
    GLOAD4(vg##S##_0, pg0+o_); GLOAD4(vu##S##_0, pu0+o_); \
    GLOAD4(vg##S##_1, pg1+o_); GLOAD4(vu##S##_1, pu1+o_); \
    GLOAD4(vg##S##_2, pg2+o_); GLOAD4(vu##S##_2, pu2+o_); \
    GLOAD4(vg##S##_3, pg3+o_); GLOAD4(vu##S##_3, pu3+o_); } while(0)

#define GU_CVW1(BG, V0, V1, V2, V3, BWI, I) do { BF4 p_; \
    p_.b[0]=(__bf16)V0[I]; p_.b[1]=(__bf16)V1[I]; p_.b[2]=(__bf16)V2[I]; p_.b[3]=(__bf16)V3[I]; \
    *(uint2*)((BG)+BWI) = p_.q; } while(0)

#define GU_CVW(S, BG, BU) do { \
    GU_CVW1(BG, vg##S##_0, vg##S##_1, vg##S##_2, vg##S##_3, bw0, 0); \
    GU_CVW1(BG, vg##S##_0, vg##S##_1, vg##S##_2, vg##S##_3, bw1, 1); \
    GU_CVW1(BG, vg##S##_0, vg##S##_1, vg##S##_2, vg##S##_3, bw2, 2); \
    GU_CVW1(BG, vg##S##_0, vg##S##_1, vg##S##_2, vg##S##_3, bw3, 3); \
    GU_CVW1(BU, vu##S##_0, vu##S##_1, vu##S##_2, vu##S##_3, bw0, 0); \
    GU_CVW1(BU, vu##S##_0, vu##S##_1, vu##S##_2, vu##S##_3, bw1, 1); \
    GU_CVW1(BU, vu##S##_0, vu##S##_1, vu##S##_2, vu##S##_3, bw2, 2); \
    GU_CVW1(BU, vu##S##_0, vu##S##_1, vu##S##_2, vu##S##_3, bw3, 3); } while(0)

#define GU_GLDA(DST, KPF) do { size_t k_ = (size_t)(KPF)*(size_t)BK; \
    gld_lds16(asrc0 + k_, (DST)+ad0); gld_lds16(asrc1 + k_, (DST)+ad1); \
    gld_lds16(asrc2 + k_, (DST)+ad2); gld_lds16(asrc3 + k_, (DST)+ad3); } while(0)

  // ---- prologue
  GU_PF(A, 0);          // 8
  GU_GLDA(As0, 0);      // -> 12
  WAITV(4);             // drain PF(0); GLDA(0):4 left
  GU_CVW(A, Bg0, Bu0);
  GU_PF(B, 1);          // -> 12
  GU_GLDA(As1, 1);      // -> 16
  WAITV(12);            // drain GLDA(0); PF(1)+GLDA(1)=12 left
  WAITL();
  BAR();

#pragma unroll 1
  for (int kt = 0; kt < NKG; kt += 2) {
    { // even: compute buf0; consume reg-set B(kt+1); refill set A(kt+2)
      int kpf = kt + 2; if (kpf > NKG-1) kpf = NKG-1;
      GU_PF(A, kpf);               // -> 20
      COMPUTE(As0, Bg0, Bu0);
      WAITV(12);                   // drain PF_B(kt+1)
      GU_CVW(B, Bg1, Bu1);
      WAITV(8);                    // drain GLDA(kt+1); keep PF(kt+2)
      WAITL();
      BAR();
      GU_GLDA(As0, kpf);           // -> 12
    }
    { // odd: mirror
      int kpf = kt + 3; if (kpf > NKG-1) kpf = NKG-1;
      GU_PF(B, kpf);
      COMPUTE(As1, Bg1, Bu1);
      WAITV(12);
      GU_CVW(A, Bg0, Bu0);
      WAITV(8);
      WAITL();
      BAR();
      GU_GLDA(As1, kpf);
    }
  }
  WAITV(0);
  WAITL();

  // ---- epilogue: SiLU(g)*u -> bf16 act
  const int rsub = (lane >> 4) * 4;
  const int csub = lane & 15;
#pragma unroll
  for (int mi = 0; mi < 4; ++mi)
#pragma unroll
    for (int j = 0; j < 4; ++j) {
      int rl = wr + mi*16 + rsub + j;
      if (m0 + rl < cnt) {
        size_t orow = (size_t)(off + m0 + rl) * I_ + n0 + wc + csub;
#pragma unroll
        for (int cg = 0; cg < 2; ++cg) {
          float g = accg[mi][cg][j];
          float u = accu[mi][cg][j];
          float sg = g / (1.0f + __expf(-g));
          act[orow + cg*16] = (__bf16)(sg * u);
        }
      }
    }
#undef GU_PF
#undef GU_CVW
#undef GU_CVW1
#undef GU_GLDA
}

// ---------------- phase 3: down GEMM -> rowbuf (f32) ----------------
// 48 KB LDS -> 3 blocks/CU. Steady outstanding 8 (PF:4 + GLDA:4).
__global__ __launch_bounds__(256, 3) void down_kernel(
    const __bf16* __restrict__ act, const float* __restrict__ dw,
    const int* __restrict__ counts, const int* __restrict__ offsets,
    const int* __restrict__ tile_e, const int* __restrict__ tile_m,
    float* __restrict__ rowbuf)
{
  extern __shared__ char smem[];
  char* As0 = smem;
  char* As1 = smem + 16384;
  char* Bs0 = smem + 32768;
  char* Bs1 = smem + 40960;

  const int id = blockIdx.x;                  // [0, 768)
  const int w  = (id & 7) * 96 + (id >> 3);   // 768 = 8*96
  const int tt = w % MAXT;
  const int ny = w / MAXT;                    // [0, 32)
  const int e  = tile_e[tt];
  const int m0 = tile_m[tt];
  const int cnt = counts[e];
  if (m0 >= cnt) return;
  const int off = offsets[e];
  const int n0 = ny * BN;

  const int tid  = threadIdx.x;
  const int lane = tid & 63;
  const int wave = tid >> 6;
  const int wr = (wave >> 1) * 64;
  const int wc = (wave & 1) * 32;

  const __bf16* asrc0; const __bf16* asrc1; const __bf16* asrc2; const __bf16* asrc3;
  int ad0, ad1, ad2, ad3;
  {
    const __bf16* s[4]; int d[4];
#pragma unroll
    for (int i = 0; i < 4; ++i) {
      int f = i*256 + tid;
      int r = f >> 3, cs = f & 7;
      int rr = m0 + r; if (rr >= cnt) rr = cnt - 1;
      s[i] = act + (size_t)(off + rr) * I_ + ((cs ^ (r & 7)) << 3);
      d[i] = f * 16;
    }
    asrc0=s[0]; asrc1=s[1]; asrc2=s[2]; asrc3=s[3];
    ad0=d[0]; ad1=d[1]; ad2=d[2]; ad3=d[3];
  }

  const int cq = tid & 15;
  const int kb = (tid >> 4) * 4;
  const float* pd0 = dw + ((size_t)e*I_ + kb + 0)*H_ + n0 + 4*cq;
  const float* pd1 = dw + ((size_t)e*I_ + kb + 1)*H_ + n0 + 4*cq;
  const float* pd2 = dw + ((size_t)e*I_ + kb + 2)*H_ + n0 + 4*cq;
  const float* pd3 = dw + ((size_t)e*I_ + kb + 3)*H_ + n0 + 4*cq;
  const int slot = kb >> 3;
  const int half = (kb & 4) << 1;
  int bw0, bw1, bw2, bw3;
  {
    int b[4];
#pragma unroll
    for (int i = 0; i < 4; ++i) {
      int c = 4*cq + i;
      b[i] = c*128 + ((slot ^ (c & 7)) << 4) + half;
    }
    bw0=b[0]; bw1=b[1]; bw2=b[2]; bw3=b[3];
  }

  f32x4 vdA_0,vdA_1,vdA_2,vdA_3;
  f32x4 vdB_0,vdB_1,vdB_2,vdB_3;

  f32x4 acc[4][2];
#pragma unroll
  for (int i = 0; i < 4; ++i)
#pragma unroll
    for (int j = 0; j < 2; ++j) acc[i][j] = (f32x4){0.f,0.f,0.f,0.f};

  auto COMPUTE = [&](const char* Ab, const char* Bb) {
#pragma unroll
    for (int kk = 0; kk < 2; ++kk) {
      const int ks = kk*4 + (lane >> 4);
      const int r0 = wr + (lane & 15);
      const int swa = (ks ^ (r0 & 7)) << 4;
      bf16x8 a0 = *(const bf16x8*)(Ab + (r0 +  0)*128 + swa);
      bf16x8 a1 = *(const bf16x8*)(Ab + (r0 + 16)*128 + swa);
      bf16x8 a2 = *(const bf16x8*)(Ab + (r0 + 32)*128 + swa);
      bf16x8 a3 = *(const bf16x8*)(Ab + (r0 + 48)*128 + swa);
      const int c0 = wc + (lane & 15);
      const int swb0 = (ks ^ (c0 & 7)) << 4;
      const int swb1 = (ks ^ ((c0+16) & 7)) << 4;
      bf16x8 b0 = *(const bf16x8*)(Bb + c0*128 + swb0);
      bf16x8 b1 = *(const bf16x8*)(Bb + (c0+16)*128 + swb1);
      acc[0][0] = __builtin_amdgcn_mfma_f32_16x16x32_bf16(a0, b0, acc[0][0], 0,0,0);
      acc[1][0] = __builtin_amdgcn_mfma_f32_16x16x32_bf16(a1, b0, acc[1][0], 0,0,0);
      acc[2][0] = __builtin_amdgcn_mfma_f32_16x16x32_bf16(a2, b0, acc[2][0], 0,0,0);
      acc[3][0] = __builtin_amdgcn_mfma_f32_16x16x32_bf16(a3, b0, acc[3][0], 0,0,0);
      acc[0][1] = __builtin_amdgcn_mfma_f32_16x16x32_bf16(a0, b1, acc[0][1], 0,0,0);
      acc[1][1] = __builtin_amdgcn_mfma_f32_16x16x32_bf16(a1, b1, acc[1][1], 0,0,0);
      acc[2][1] = __builtin_amdgcn_mfma_f32_16x16x32_bf16(a2, b1, acc[2][1], 0,0,0);
      acc[3][1] = __builtin_amdgcn_mfma_f32_16x16x32_bf16(a3, b1, acc[3][1], 0,0,0);
    }
  };

#define DN_PF(S, KPF) do { size_t o_ = (size_t)(KPF)*(size_t)BK*(size_t)H_; \
    GLOAD4(vd##S##_0, pd0+o_); GLOAD4(vd##S##_1, pd1+o_); \
    GLOAD4(vd##S##_2, pd2+o_); GLOAD4(vd##S##_3, pd3+o_); } while(0)

#define DN_CVW1(BB, V0, V1, V2, V3, BWI, I) do { BF4 p_; \
    p_.b[0]=(__bf16)V0[I]; p_.b[1]=(__bf16)V1[I]; p_.b[2]=(__bf16)V2[I]; p_.b[3]=(__bf16)V3[I]; \
    *(uint2*)((BB)+BWI) = p_.q; } while(0)

#define DN_CVW(S, BB) do { \
    DN_CVW1(BB, vd##S##_0, vd##S##_1, vd##S##_2, vd##S##_3, bw0, 0); \
    DN_CVW1(BB, vd##S##_0, vd##S##_1, vd##S##_2, vd##S##_3, bw1, 1); \
    DN_CVW1(BB, vd##S##_0, vd##S##_1, vd##S##_2, vd##S##_3, bw2, 2); \
    DN_CVW1(BB, vd##S##_0, vd##S##_1, vd##S##_2, vd##S##_3, bw3, 3); } while(0)

#define DN_GLDA(DST, KPF) do { size_t k_ = (size_t)(KPF)*(size_t)BK; \
    gld_lds16(asrc0 + k_, (DST)+ad0); gld_lds16(asrc1 + k_, (DST)+ad1); \
    gld_lds16(asrc2 + k_, (DST)+ad2); gld_lds16(asrc3 + k_, (DST)+ad3); } while(0)

  DN_PF(A, 0);          // 4
  DN_GLDA(As0, 0);      // -> 8
  WAITV(4);             // drain PF(0)
  DN_CVW(A, Bs0);
  DN_PF(B, 1);          // -> 8
  DN_GLDA(As1, 1);      // -> 12
  WAITV(8);             // drain GLDA(0); PF(1)+GLDA(1)=8 left
  WAITL();
  BAR();

#pragma unroll 1
  for (int kt = 0; kt < NKD; kt += 2) {
    {
      int kpf = kt + 2; if (kpf > NKD-1) kpf = NKD-1;
      DN_PF(A, kpf);               // -> 12
      COMPUTE(As0, Bs0);
      WAITV(8);                    // drain PF_B(kt+1)
      DN_CVW(B, Bs1);
      WAITV(4);                    // drain GLDA(kt+1)
      WAITL();
      BAR();
      DN_GLDA(As0, kpf);           // -> 8
    }
    {
      int kpf = kt + 3; if (kpf > NKD-1) kpf = NKD-1;
      DN_PF(B, kpf);
      COMPUTE(As1, Bs1);
      WAITV(8);
      DN_CVW(A, Bs0);
      WAITV(4);
      WAITL();
      BAR();
      DN_GLDA(As1, kpf);
    }
  }
  WAITV(0);
  WAITL();

  const int rsub = (lane >> 4) * 4;
  const int csub = lane & 15;
#pragma unroll
  for (int mi = 0; mi < 4; ++mi)
#pragma unroll
    for (int j = 0; j < 4; ++j) {
      int rl = wr + mi*16 + rsub + j;
      if (m0 + rl < cnt) {
        size_t orow = (size_t)(off + m0 + rl) * H_ + n0 + wc + csub;
#pragma unroll
        for (int cg = 0; cg < 2; ++cg)
          rowbuf[orow + cg*16] = acc[mi][cg][j];
      }
    }
#undef DN_PF
#undef DN_CVW
#undef DN_CVW1
#undef DN_GLDA
}

// ---------------- phase 4: weighted combine ----------------
__global__ void combine_kernel(const float* __restrict__ ew, const int* __restrict__ row_of,
                               const float* __restrict__ rowbuf, float* __restrict__ out) {
  int idx = blockIdx.x * 256 + threadIdx.x;   // over B_*H_/4
  int t  = idx >> 9;                          // H_/4 = 512
  int h4 = idx & 511;
  float w0 = ew[t*2+0], w1 = ew[t*2+1];
  int r0 = row_of[t*2+0], r1 = row_of[t*2+1];
  float4 a = *(const float4*)(rowbuf + (size_t)r0*H_ + h4*4);
  float4 b = *(const float4*)(rowbuf + (size_t)r1*H_ + h4*4);
  float4 o;
  o.x = w0*a.x + w1*b.x; o.y = w0*a.y + w1*b.y;
  o.z = w0*a.z + w1*b.z; o.w = w0*a.w + w1*b.w;
  *(float4*)(out + (size_t)idx*4) = o;
}

extern "C" void kernel_launch(void* const* d_in, const int* in_sizes, int n_in,
                              void* d_out, int out_size, void* d_ws, size_t ws_size,
                              hipStream_t stream) {
  const float* x   = (const float*)d_in[0];
  const int*   ids = (const int*)d_in[1];
  const float* ew  = (const float*)d_in[2];
  const float* gw  = (const float*)d_in[3];
  const float* uw  = (const float*)d_in[4];
  const float* dwn = (const float*)d_in[5];
  float* out = (float*)d_out;

  char* ws = (char*)d_ws;
  int* counts  = (int*)ws;          // 8
  int* offsets = counts + 8;        // 8
  int* tlist   = offsets + 8;       // NROWS
  int* row_of  = tlist + NROWS;     // NROWS
  int* tile_e  = row_of + NROWS;    // MAXT
  int* tile_m  = tile_e + MAXT;     // MAXT
  __bf16* xb   = (__bf16*)(ws + 32768);
  __bf16* act  = (__bf16*)(ws + 32768 + (size_t)B_*H_*2);
  float* rowbuf = (float*)(ws + 32768 + (size_t)B_*H_*2 + (size_t)NROWS*I_*2);

  hipFuncSetAttribute(reinterpret_cast<const void*>(&gateup_kernel),
                      hipFuncAttributeMaxDynamicSharedMemorySize, 65536);
  hipFuncSetAttribute(reinterpret_cast<const void*>(&down_kernel),
                      hipFuncAttributeMaxDynamicSharedMemorySize, 49152);

  cvtx_kernel<<<B_*H_/(256*8), 256, 0, stream>>>(x, xb);
  route_kernel<<<1, 256, 0, stream>>>(ids, counts, offsets, tlist, row_of, tile_e, tile_m);

  gateup_kernel<<<MAXT*NYG, 256, 65536, stream>>>(xb, gw, uw, counts, offsets, tlist,
                                                  tile_e, tile_m, act);

  down_kernel<<<MAXT*NYD, 256, 49152, stream>>>(act, dwn, counts, offsets,
                                                tile_e, tile_m, rowbuf);

  combine_kernel<<<(B_*H_/4)/256, 256, 0, stream>>>(ew, row_of, rowbuf, out);
}

// Round 8
// 415.103 us; speedup vs baseline: 1.3586x; 1.0828x over previous
//
#include <hip/hip_runtime.h>
#include <hip/hip_bf16.h>

#define E_ 8
#define H_ 2048
#define I_ 5632
#define B_ 1024
#define K_ 2
#define NROWS (B_*K_)

#define BM 128
#define BN 64
#define BK 64
#define MAXT 24           // sum_e ceil(cnt_e/128) <= 16 + 8
#define NKG (H_/BK)       // 32
#define NKD (I_/BK)       // 88
#define NYG (I_/BN)       // 88
#define NYD (H_/BN)       // 32

typedef __attribute__((ext_vector_type(8))) __bf16 bf16x8;
typedef __attribute__((ext_vector_type(4))) float f32x4;

union BF4 { __bf16 b[4]; uint2 q; };
union BF8 { __bf16 b[8]; uint4 q; };

__device__ __forceinline__ void gld_lds16(const void* g, void* l) {
  __builtin_amdgcn_global_load_lds(
      (const __attribute__((address_space(1))) void*)g,
      (__attribute__((address_space(3))) void*)l, 16, 0, 0);
}

#define GLOAD4(dst, ptr) asm volatile("global_load_dwordx4 %0, %1, off" : "=v"(dst) : "v"(ptr))
#define WAITV(N) do { asm volatile("s_waitcnt vmcnt(" #N ")" ::: "memory"); __builtin_amdgcn_sched_barrier(0); } while(0)
#define WAITL()  do { asm volatile("s_waitcnt lgkmcnt(0)" ::: "memory"); __builtin_amdgcn_sched_barrier(0); } while(0)
#define BAR()    __builtin_amdgcn_s_barrier()

// bank-spread swizzle: over the dwordx4 write pattern (fixed i, 16 cq lanes)
// AND over 16 consecutive read cols, MSK covers all 8 slot values twice.
#define MSK(c) (((c)&7) ^ (((c)>>2)&7))

// ---------------- phase 0: x (f32) -> xb (bf16) ----------------
__global__ void cvtx_kernel(const float* __restrict__ x, __bf16* __restrict__ xb) {
  int i = (blockIdx.x * 256 + threadIdx.x) * 8;
  float4 a = *(const float4*)(x + i);
  float4 b = *(const float4*)(x + i + 4);
  BF8 r;
  r.b[0] = (__bf16)a.x; r.b[1] = (__bf16)a.y; r.b[2] = (__bf16)a.z; r.b[3] = (__bf16)a.w;
  r.b[4] = (__bf16)b.x; r.b[5] = (__bf16)b.y; r.b[6] = (__bf16)b.z; r.b[7] = (__bf16)b.w;
  *(uint4*)(xb + i) = r.q;
}

// ---------------- phase 1: routing + dense tile list ----------------
__global__ void route_kernel(const int* __restrict__ ids,
                             int* __restrict__ counts, int* __restrict__ offsets,
                             int* __restrict__ tlist, int* __restrict__ row_of,
                             int* __restrict__ tile_e, int* __restrict__ tile_m) {
  __shared__ int sc[E_], sp[E_], so[E_];
  int t = threadIdx.x;
  if (t < E_) { sc[t] = 0; sp[t] = 0; }
  __syncthreads();
  for (int idx = t; idx < NROWS; idx += 256) atomicAdd(&sc[ids[idx]], 1);
  __syncthreads();
  if (t == 0) {
    int acc = 0;
    for (int e = 0; e < E_; ++e) { so[e] = acc; acc += sc[e]; }
    int nt = 0;
    for (int e = 0; e < E_; ++e)
      for (int m0 = 0; m0 < sc[e]; m0 += BM) { tile_e[nt] = e; tile_m[nt] = m0; ++nt; }
    for (; nt < MAXT; ++nt) { tile_e[nt] = 0; tile_m[nt] = 0x7FFFFFFF; }
  }
  __syncthreads();
  for (int idx = t; idx < NROWS; idx += 256) {
    int e = ids[idx];
    int slot = atomicAdd(&sp[e], 1);
    int row = so[e] + slot;
    tlist[row] = idx / K_;
    row_of[idx] = row;
  }
  if (t < E_) { counts[t] = sc[t]; offsets[t] = so[t]; }
}

// ---------------- phase 2: gate+up dual GEMM + SiLU (bf16 act) ----------------
// 256 thr (4 waves 2m x 2n over 128x64), 64 KB LDS -> 2 blocks/CU.
// Counted-vmcnt: steady outstanding 12 (PF:8 + GLDA:4), one s_barrier/k-step.
__global__ __launch_bounds__(256, 2) void gateup_kernel(
    const __bf16* __restrict__ xb, const float* __restrict__ gw,
    const float* __restrict__ uw, const int* __restrict__ counts,
    const int* __restrict__ offsets, const int* __restrict__ tlist,
    const int* __restrict__ tile_e, const int* __restrict__ tile_m,
    __bf16* __restrict__ act)
{
  extern __shared__ char smem[];
  char* As0 = smem;                 // 16384 each (128 rows x 128B, swizzled)
  char* As1 = smem + 16384;
  char* Bg0 = smem + 32768;         // 8192 each (64 cols x 128B, swizzled)
  char* Bg1 = smem + 40960;
  char* Bu0 = smem + 49152;
  char* Bu1 = smem + 57344;

  const int id = blockIdx.x;                  // [0, 2112)
  const int w  = (id & 7) * 264 + (id >> 3);  // XCD chunking (2112 = 8*264)
  const int tt = w % MAXT;
  const int ny = w / MAXT;                    // [0, 88)
  const int e  = tile_e[tt];
  const int m0 = tile_m[tt];
  const int cnt = counts[e];
  if (m0 >= cnt) return;
  const int off = offsets[e];
  const int n0 = ny * BN;

  const int tid  = threadIdx.x;
  const int lane = tid & 63;
  const int wave = tid >> 6;         // 0..3
  const int wr = (wave >> 1) * 64;   // 0,64
  const int wc = (wave & 1) * 32;    // 0,32

  // ---- A staging: 4 granules/thread, LDS linear, source slot-swizzled
  const __bf16* asrc0; const __bf16* asrc1; const __bf16* asrc2; const __bf16* asrc3;
  int ad0, ad1, ad2, ad3;
  {
    const __bf16* s[4]; int d[4];
#pragma unroll
    for (int i = 0; i < 4; ++i) {
      int f = i*256 + tid;
      int r = f >> 3, cs = f & 7;
      int rr = m0 + r; if (rr >= cnt) rr = cnt - 1;
      int tok = tlist[off + rr];
      s[i] = xb + (size_t)tok * H_ + ((cs ^ (r & 7)) << 3);
      d[i] = f * 16;
    }
    asrc0=s[0]; asrc1=s[1]; asrc2=s[2]; asrc3=s[3];
    ad0=d[0]; ad1=d[1]; ad2=d[2]; ad3=d[3];
  }

  // ---- B staging: thread owns cols 4cq..4cq+3, k-rows kb..kb+3 (dwordx4)
  const int cq = tid & 15;           // col-chunk of 4 floats
  const int kb = (tid >> 4) * 4;     // 0..60
  const float* pg0 = gw + ((size_t)e*H_ + kb + 0)*I_ + n0 + 4*cq;
  const float* pg1 = gw + ((size_t)e*H_ + kb + 1)*I_ + n0 + 4*cq;
  const float* pg2 = gw + ((size_t)e*H_ + kb + 2)*I_ + n0 + 4*cq;
  const float* pg3 = gw + ((size_t)e*H_ + kb + 3)*I_ + n0 + 4*cq;
  const float* pu0 = uw + ((size_t)e*H_ + kb + 0)*I_ + n0 + 4*cq;
  const float* pu1 = uw + ((size_t)e*H_ + kb + 1)*I_ + n0 + 4*cq;
  const float* pu2 = uw + ((size_t)e*H_ + kb + 2)*I_ + n0 + 4*cq;
  const float* pu3 = uw + ((size_t)e*H_ + kb + 3)*I_ + n0 + 4*cq;
  const int slot = kb >> 3;
  const int half = (kb & 4) << 1;    // 0 or 8
  int bw0, bw1, bw2, bw3;
  {
    int b[4];
#pragma unroll
    for (int i = 0; i < 4; ++i) {
      int c = 4*cq + i;
      b[i] = c*128 + ((slot ^ MSK(c)) << 4) + half;
    }
    bw0=b[0]; bw1=b[1]; bw2=b[2]; bw3=b[3];
  }

  f32x4 vgA_0,vgA_1,vgA_2,vgA_3, vuA_0,vuA_1,vuA_2,vuA_3;
  f32x4 vgB_0,vgB_1,vgB_2,vgB_3, vuB_0,vuB_1,vuB_2,vuB_3;

  f32x4 accg[4][2], accu[4][2];
#pragma unroll
  for (int i = 0; i < 4; ++i)
#pragma unroll
    for (int j = 0; j < 2; ++j) {
      accg[i][j] = (f32x4){0.f,0.f,0.f,0.f};
      accu[i][j] = (f32x4){0.f,0.f,0.f,0.f};
    }

  auto COMPUTE = [&](const char* Ab, const char* Bgb, const char* Bub) {
#pragma unroll
    for (int kk = 0; kk < 2; ++kk) {
      const int ks = kk*4 + (lane >> 4);
      const int r0 = wr + (lane & 15);
      const int swa = (ks ^ (r0 & 7)) << 4;
      bf16x8 a0 = *(const bf16x8*)(Ab + (r0 +  0)*128 + swa);
      bf16x8 a1 = *(const bf16x8*)(Ab + (r0 + 16)*128 + swa);
      bf16x8 a2 = *(const bf16x8*)(Ab + (r0 + 32)*128 + swa);
      bf16x8 a3 = *(const bf16x8*)(Ab + (r0 + 48)*128 + swa);
      const int c0 = wc + (lane & 15);
      const int swb0 = (ks ^ MSK(c0)) << 4;
      const int swb1 = swb0 ^ (4 << 4);     // MSK(c+16) = MSK(c) ^ 4
      bf16x8 g0 = *(const bf16x8*)(Bgb + c0*128 + swb0);
      bf16x8 g1 = *(const bf16x8*)(Bgb + (c0+16)*128 + swb1);
      bf16x8 u0 = *(const bf16x8*)(Bub + c0*128 + swb0);
      bf16x8 u1 = *(const bf16x8*)(Bub + (c0+16)*128 + swb1);
      accg[0][0] = __builtin_amdgcn_mfma_f32_16x16x32_bf16(a0, g0, accg[0][0], 0,0,0);
      accg[1][0] = __builtin_amdgcn_mfma_f32_16x16x32_bf16(a1, g0, accg[1][0], 0,0,0);
      accg[2][0] = __builtin_amdgcn_mfma_f32_16x16x32_bf16(a2, g0, accg[2][0], 0,0,0);
      accg[3][0] = __builtin_amdgcn_mfma_f32_16x16x32_bf16(a3, g0, accg[3][0], 0,0,0);
      accg[0][1] = __builtin_amdgcn_mfma_f32_16x16x32_bf16(a0, g1, accg[0][1], 0,0,0);
      accg[1][1] = __builtin_amdgcn_mfma_f32_16x16x32_bf16(a1, g1, accg[1][1], 0,0,0);
      accg[2][1] = __builtin_amdgcn_mfma_f32_16x16x32_bf16(a2, g1, accg[2][1], 0,0,0);
      accg[3][1] = __builtin_amdgcn_mfma_f32_16x16x32_bf16(a3, g1, accg[3][1], 0,0,0);
      accu[0][0] = __builtin_amdgcn_mfma_f32_16x16x32_bf16(a0, u0, accu[0][0], 0,0,0);
      accu[1][0] = __builtin_amdgcn_mfma_f32_16x16x32_bf16(a1, u0, accu[1][0], 0,0,0);
      accu[2][0] = __builtin_amdgcn_mfma_f32_16x16x32_bf16(a2, u0, accu[2][0], 0,0,0);
      accu[3][0] = __builtin_amdgcn_mfma_f32_16x16x32_bf16(a3, u0, accu[3][0], 0,0,0);
      accu[0][1] = __builtin_amdgcn_mfma_f32_16x16x32_bf16(a0, u1, accu[0][1], 0,0,0);
      accu[1][1] = __builtin_amdgcn_mfma_f32_16x16x32_bf16(a1, u1, accu[1][1], 0,0,0);
      accu[2][1] = __builtin_amdgcn_mfma_f32_16x16x32_bf16(a2, u1, accu[2][1], 0,0,0);
      accu[3][1] = __builtin_amdgcn_mfma_f32_16x16x32_bf16(a3, u1, accu[3][1], 0,0,0);
    }
  };

#define GU_PF(S, KPF) do { size_t o_ = (size_t)(KPF)*(size_t)BK*(size_t)I_; \
    GLOAD4(vg##S##_0, pg0+o_); GLOAD4(vu##S##_0, pu0+o_); \
    GLOAD4(vg##S##_1, pg1+o_); GLOAD4(vu##S##_1, pu1+o_); \
    GLOAD4(vg##S##_2, pg2+o_); GLOAD4(vu##S##_2, pu2+o_); \
    GLOAD4(vg##S##_3, pg3+o_); GLOAD4(vu##S##_3, pu3+o_); } while(0)

#define GU_CVW1(BG, V0, V1, V2, V3, BWI, I) do { BF4 p_; \
    p_.b[0]=(__bf16)V0[I]; p_.b[1]=(__bf16)V1[I]; p_.b[2]=(__bf16)V2[I]; p_.b[3]=(__bf16)V3[I]; \
    *(uint2*)((BG)+BWI) = p_.q; } while(0)

#define GU_CVW(S, BG, BU) do { \
    GU_CVW1(BG, vg##S##_0, vg##S##_1, vg##S##_2, vg##S##_3, bw0, 0); \
    GU_CVW1(BG, vg##S##_0, vg##S##_1, vg##S##_2, vg##S##_3, bw1, 1); \
    GU_CVW1(BG, vg##S##_0, vg##S##_1, vg##S##_2, vg##S##_3, bw2, 2); \
    GU_CVW1(BG, vg##S##_0, vg##S##_1, vg##S##_2, vg##S##_3, bw3, 3); \
    GU_CVW1(BU, vu##S##_0, vu##S##_1, vu##S##_2, vu##S##_3, bw0, 0); \
    GU_CVW1(BU, vu##S##_0, vu##S##_1, vu##S##_2, vu##S##_3, bw1, 1); \
    GU_CVW1(BU, vu##S##_0, vu##S##_1, vu##S##_2, vu##S##_3, bw2, 2); \
    GU_CVW1(BU, vu##S##_0, vu##S##_1, vu##S##_2, vu##S##_3, bw3, 3); } while(0)

#define GU_GLDA(DST, KPF) do { size_t k_ = (size_t)(KPF)*(size_t)BK; \
    gld_lds16(asrc0 + k_, (DST)+ad0); gld_lds16(asrc1 + k_, (DST)+ad1); \
    gld_lds16(asrc2 + k_, (DST)+ad2); gld_lds16(asrc3 + k_, (DST)+ad3); } while(0)

  // ---- prologue
  GU_PF(A, 0);          // 8
  GU_GLDA(As0, 0);      // -> 12
  WAITV(4);             // drain PF(0); GLDA(0):4 left
  GU_CVW(A, Bg0, Bu0);
  GU_PF(B, 1);          // -> 12
  GU_GLDA(As1, 1);      // -> 16
  WAITV(12);            // drain GLDA(0); PF(1)+GLDA(1)=12 left
  WAITL();
  BAR();

#pragma unroll 1
  for (int kt = 0; kt < NKG; kt += 2) {
    { // even: compute buf0; consume reg-set B(kt+1); refill set A(kt+2)
      int kpf = kt + 2; if (kpf > NKG-1) kpf = NKG-1;
      GU_PF(A, kpf);               // -> 20
      COMPUTE(As0, Bg0, Bu0);
      WAITV(12);                   // drain PF_B(kt+1)
      GU_CVW(B, Bg1, Bu1);
      WAITV(8);                    // drain GLDA(kt+1); keep PF(kt+2)
      WAITL();
      BAR();
      GU_GLDA(As0, kpf);           // -> 12
    }
    { // odd: mirror
      int kpf = kt + 3; if (kpf > NKG-1) kpf = NKG-1;
      GU_PF(B, kpf);
      COMPUTE(As1, Bg1, Bu1);
      WAITV(12);
      GU_CVW(A, Bg0, Bu0);
      WAITV(8);
      WAITL();
      BAR();
      GU_GLDA(As1, kpf);
    }
  }
  WAITV(0);
  WAITL();

  // ---- epilogue: SiLU(g)*u -> bf16 act
  const int rsub = (lane >> 4) * 4;
  const int csub = lane & 15;
#pragma unroll
  for (int mi = 0; mi < 4; ++mi)
#pragma unroll
    for (int j = 0; j < 4; ++j) {
      int rl = wr + mi*16 + rsub + j;
      if (m0 + rl < cnt) {
        size_t orow = (size_t)(off + m0 + rl) * I_ + n0 + wc + csub;
#pragma unroll
        for (int cg = 0; cg < 2; ++cg) {
          float g = accg[mi][cg][j];
          float u = accu[mi][cg][j];
          float sg = g / (1.0f + __expf(-g));
          act[orow + cg*16] = (__bf16)(sg * u);
        }
      }
    }
#undef GU_PF
#undef GU_CVW
#undef GU_CVW1
#undef GU_GLDA
}

// ---------------- phase 3: down GEMM -> rowbuf (f32) ----------------
// 48 KB LDS -> 3 blocks/CU. Steady outstanding 8 (PF:4 + GLDA:4).
__global__ __launch_bounds__(256, 3) void down_kernel(
    const __bf16* __restrict__ act, const float* __restrict__ dw,
    const int* __restrict__ counts, const int* __restrict__ offsets,
    const int* __restrict__ tile_e, const int* __restrict__ tile_m,
    float* __restrict__ rowbuf)
{
  extern __shared__ char smem[];
  char* As0 = smem;
  char* As1 = smem + 16384;
  char* Bs0 = smem + 32768;
  char* Bs1 = smem + 40960;

  const int id = blockIdx.x;                  // [0, 768)
  const int w  = (id & 7) * 96 + (id >> 3);   // 768 = 8*96
  const int tt = w % MAXT;
  const int ny = w / MAXT;                    // [0, 32)
  const int e  = tile_e[tt];
  const int m0 = tile_m[tt];
  const int cnt = counts[e];
  if (m0 >= cnt) return;
  const int off = offsets[e];
  const int n0 = ny * BN;

  const int tid  = threadIdx.x;
  const int lane = tid & 63;
  const int wave = tid >> 6;
  const int wr = (wave >> 1) * 64;
  const int wc = (wave & 1) * 32;

  const __bf16* asrc0; const __bf16* asrc1; const __bf16* asrc2; const __bf16* asrc3;
  int ad0, ad1, ad2, ad3;
  {
    const __bf16* s[4]; int d[4];
#pragma unroll
    for (int i = 0; i < 4; ++i) {
      int f = i*256 + tid;
      int r = f >> 3, cs = f & 7;
      int rr = m0 + r; if (rr >= cnt) rr = cnt - 1;
      s[i] = act + (size_t)(off + rr) * I_ + ((cs ^ (r & 7)) << 3);
      d[i] = f * 16;
    }
    asrc0=s[0]; asrc1=s[1]; asrc2=s[2]; asrc3=s[3];
    ad0=d[0]; ad1=d[1]; ad2=d[2]; ad3=d[3];
  }

  const int cq = tid & 15;
  const int kb = (tid >> 4) * 4;
  const float* pd0 = dw + ((size_t)e*I_ + kb + 0)*H_ + n0 + 4*cq;
  const float* pd1 = dw + ((size_t)e*I_ + kb + 1)*H_ + n0 + 4*cq;
  const float* pd2 = dw + ((size_t)e*I_ + kb + 2)*H_ + n0 + 4*cq;
  const float* pd3 = dw + ((size_t)e*I_ + kb + 3)*H_ + n0 + 4*cq;
  const int slot = kb >> 3;
  const int half = (kb & 4) << 1;
  int bw0, bw1, bw2, bw3;
  {
    int b[4];
#pragma unroll
    for (int i = 0; i < 4; ++i) {
      int c = 4*cq + i;
      b[i] = c*128 + ((slot ^ MSK(c)) << 4) + half;
    }
    bw0=b[0]; bw1=b[1]; bw2=b[2]; bw3=b[3];
  }

  f32x4 vdA_0,vdA_1,vdA_2,vdA_3;
  f32x4 vdB_0,vdB_1,vdB_2,vdB_3;

  f32x4 acc[4][2];
#pragma unroll
  for (int i = 0; i < 4; ++i)
#pragma unroll
    for (int j = 0; j < 2; ++j) acc[i][j] = (f32x4){0.f,0.f,0.f,0.f};

  auto COMPUTE = [&](const char* Ab, const char* Bb) {
#pragma unroll
    for (int kk = 0; kk < 2; ++kk) {
      const int ks = kk*4 + (lane >> 4);
      const int r0 = wr + (lane & 15);
      const int swa = (ks ^ (r0 & 7)) << 4;
      bf16x8 a0 = *(const bf16x8*)(Ab + (r0 +  0)*128 + swa);
      bf16x8 a1 = *(const bf16x8*)(Ab + (r0 + 16)*128 + swa);
      bf16x8 a2 = *(const bf16x8*)(Ab + (r0 + 32)*128 + swa);
      bf16x8 a3 = *(const bf16x8*)(Ab + (r0 + 48)*128 + swa);
      const int c0 = wc + (lane & 15);
      const int swb0 = (ks ^ MSK(c0)) << 4;
      const int swb1 = swb0 ^ (4 << 4);
      bf16x8 b0 = *(const bf16x8*)(Bb + c0*128 + swb0);
      bf16x8 b1 = *(const bf16x8*)(Bb + (c0+16)*128 + swb1);
      acc[0][0] = __builtin_amdgcn_mfma_f32_16x16x32_bf16(a0, b0, acc[0][0], 0,0,0);
      acc[1][0] = __builtin_amdgcn_mfma_f32_16x16x32_bf16(a1, b0, acc[1][0], 0,0,0);
      acc[2][0] = __builtin_amdgcn_mfma_f32_16x16x32_bf16(a2, b0, acc[2][0], 0,0,0);
      acc[3][0] = __builtin_amdgcn_mfma_f32_16x16x32_bf16(a3, b0, acc[3][0], 0,0,0);
      acc[0][1] = __builtin_amdgcn_mfma_f32_16x16x32_bf16(a0, b1, acc[0][1], 0,0,0);
      acc[1][1] = __builtin_amdgcn_mfma_f32_16x16x32_bf16(a1, b1, acc[1][1], 0,0,0);
      acc[2][1] = __builtin_amdgcn_mfma_f32_16x16x32_bf16(a2, b1, acc[2][1], 0,0,0);
      acc[3][1] = __builtin_amdgcn_mfma_f32_16x16x32_bf16(a3, b1, acc[3][1], 0,0,0);
    }
  };

#define DN_PF(S, KPF) do { size_t o_ = (size_t)(KPF)*(size_t)BK*(size_t)H_; \
    GLOAD4(vd##S##_0, pd0+o_); GLOAD4(vd##S##_1, pd1+o_); \
    GLOAD4(vd##S##_2, pd2+o_); GLOAD4(vd##S##_3, pd3+o_); } while(0)

#define DN_CVW1(BB, V0, V1, V2, V3, BWI, I) do { BF4 p_; \
    p_.b[0]=(__bf16)V0[I]; p_.b[1]=(__bf16)V1[I]; p_.b[2]=(__bf16)V2[I]; p_.b[3]=(__bf16)V3[I]; \
    *(uint2*)((BB)+BWI) = p_.q; } while(0)

#define DN_CVW(S, BB) do { \
    DN_CVW1(BB, vd##S##_0, vd##S##_1, vd##S##_2, vd##S##_3, bw0, 0); \
    DN_CVW1(BB, vd##S##_0, vd##S##_1, vd##S##_2, vd##S##_3, bw1, 1); \
    DN_CVW1(BB, vd##S##_0, vd##S##_1, vd##S##_2, vd##S##_3, bw2, 2); \
    DN_CVW1(BB, vd##S##_0, vd##S##_1, vd##S##_2, vd##S##_3, bw3, 3); } while(0)

#define DN_GLDA(DST, KPF) do { size_t k_ = (size_t)(KPF)*(size_t)BK; \
    gld_lds16(asrc0 + k_, (DST)+ad0); gld_lds16(asrc1 + k_, (DST)+ad1); \
    gld_lds16(asrc2 + k_, (DST)+ad2); gld_lds16(asrc3 + k_, (DST)+ad3); } while(0)

  DN_PF(A, 0);          // 4
  DN_GLDA(As0, 0);      // -> 8
  WAITV(4);             // drain PF(0)
  DN_CVW(A, Bs0);
  DN_PF(B, 1);          // -> 8
  DN_GLDA(As1, 1);      // -> 12
  WAITV(8);             // drain GLDA(0); PF(1)+GLDA(1)=8 left
  WAITL();
  BAR();

#pragma unroll 1
  for (int kt = 0; kt < NKD; kt += 2) {
    {
      int kpf = kt + 2; if (kpf > NKD-1) kpf = NKD-1;
      DN_PF(A, kpf);               // -> 12
      COMPUTE(As0, Bs0);
      WAITV(8);                    // drain PF_B(kt+1)
      DN_CVW(B, Bs1);
      WAITV(4);                    // drain GLDA(kt+1)
      WAITL();
      BAR();
      DN_GLDA(As0, kpf);           // -> 8
    }
    {
      int kpf = kt + 3; if (kpf > NKD-1) kpf = NKD-1;
      DN_PF(B, kpf);
      COMPUTE(As1, Bs1);
      WAITV(8);
      DN_CVW(A, Bs0);
      WAITV(4);
      WAITL();
      BAR();
      DN_GLDA(As1, kpf);
    }
  }
  WAITV(0);
  WAITL();

  const int rsub = (lane >> 4) * 4;
  const int csub = lane & 15;
#pragma unroll
  for (int mi = 0; mi < 4; ++mi)
#pragma unroll
    for (int j = 0; j < 4; ++j) {
      int rl = wr + mi*16 + rsub + j;
      if (m0 + rl < cnt) {
        size_t orow = (size_t)(off + m0 + rl) * H_ + n0 + wc + csub;
#pragma unroll
        for (int cg = 0; cg < 2; ++cg)
          rowbuf[orow + cg*16] = acc[mi][cg][j];
      }
    }
#undef DN_PF
#undef DN_CVW
#undef DN_CVW1
#undef DN_GLDA
}

// ---------------- phase 4: weighted combine ----------------
__global__ void combine_kernel(const float* __restrict__ ew, const int* __restrict__ row_of,
                               const float* __restrict__ rowbuf, float* __restrict__ out) {
  int idx = blockIdx.x * 256 + threadIdx.x;   // over B_*H_/4
  int t  = idx >> 9;                          // H_/4 = 512
  int h4 = idx & 511;
  float w0 = ew[t*2+0], w1 = ew[t*2+1];
  int r0 = row_of[t*2+0], r1 = row_of[t*2+1];
  float4 a = *(const float4*)(rowbuf + (size_t)r0*H_ + h4*4);
  float4 b = *(const float4*)(rowbuf + (size_t)r1*H_ + h4*4);
  float4 o;
  o.x = w0*a.x + w1*b.x; o.y = w0*a.y + w1*b.y;
  o.z = w0*a.z + w1*b.z; o.w = w0*a.w + w1*b.w;
  *(float4*)(out + (size_t)idx*4) = o;
}

extern "C" void kernel_launch(void* const* d_in, const int* in_sizes, int n_in,
                              void* d_out, int out_size, void* d_ws, size_t ws_size,
                              hipStream_t stream) {
  const float* x   = (const float*)d_in[0];
  const int*   ids = (const int*)d_in[1];
  const float* ew  = (const float*)d_in[2];
  const float* gw  = (const float*)d_in[3];
  const float* uw  = (const float*)d_in[4];
  const float* dwn = (const float*)d_in[5];
  float* out = (float*)d_out;

  char* ws = (char*)d_ws;
  int* counts  = (int*)ws;          // 8
  int* offsets = counts + 8;        // 8
  int* tlist   = offsets + 8;       // NROWS
  int* row_of  = tlist + NROWS;     // NROWS
  int* tile_e  = row_of + NROWS;    // MAXT
  int* tile_m  = tile_e + MAXT;     // MAXT
  __bf16* xb   = (__bf16*)(ws + 32768);
  __bf16* act  = (__bf16*)(ws + 32768 + (size_t)B_*H_*2);
  float* rowbuf = (float*)(ws + 32768 + (size_t)B_*H_*2 + (size_t)NROWS*I_*2);

  hipFuncSetAttribute(reinterpret_cast<const void*>(&gateup_kernel),
                      hipFuncAttributeMaxDynamicSharedMemorySize, 65536);
  hipFuncSetAttribute(reinterpret_cast<const void*>(&down_kernel),
                      hipFuncAttributeMaxDynamicSharedMemorySize, 49152);

  cvtx_kernel<<<B_*H_/(256*8), 256, 0, stream>>>(x, xb);
  route_kernel<<<1, 256, 0, stream>>>(ids, counts, offsets, tlist, row_of, tile_e, tile_m);

  gateup_kernel<<<MAXT*NYG, 256, 65536, stream>>>(xb, gw, uw, counts, offsets, tlist,
                                                  tile_e, tile_m, act);

  down_kernel<<<MAXT*NYD, 256, 49152, stream>>>(act, dwn, counts, offsets,
                                                tile_e, tile_m, rowbuf);

  combine_kernel<<<(B_*H_/4)/256, 256, 0, stream>>>(ew, row_of, rowbuf, out);
}